// Round 1
// baseline (837.423 us; speedup 1.0000x reference)
//
#include <hip/hip_runtime.h>
#include <math.h>

#define NN 10000
#define NE 100000

static constexpr float C_TANH  = 1.5927f;
static constexpr float SQ3     = 1.7320508075688772f;
static constexpr float H_SCALE = 0.4472135954999579f;   // C_RELU / sqrt(10)
static constexpr float A0      = 0.11785113019775793f;  // sqrt(1/72)
static constexpr float A0S3    = 0.06804138174397717f;  // sqrt(1/216)
static constexpr float B0      = 0.20412414523193154f;  // sqrt(1/24)
static constexpr float B0S3    = 0.11785113019775793f;  // sqrt(1/72)
static constexpr float S32     = 0.1767766952966369f;   // 1/sqrt(32)
static constexpr float S16     = 0.25f;                 // 1/sqrt(16)
static constexpr float S8      = 0.3535533905932738f;   // 1/sqrt(8)

// ---------------------------------------------------------------------------
// Prep: transpose fc*_w2 to column-major (16 contiguous floats per output
// column) with 1/sqrt(16) and the per-region output scales folded in.
// Ft1: 2304 cols x 16 ; Ft2: 576 cols x 16
// ---------------------------------------------------------------------------
__global__ void prep_kernel(const float* __restrict__ fc1_w2,
                            const float* __restrict__ fc2_w2,
                            float* __restrict__ Ft1,
                            float* __restrict__ Ft2) {
  int t = blockIdx.x * blockDim.x + threadIdx.x;
  if (t < 2304) {
    // regions: [0,1152)=a0  [1152,1728)=a0/sq3  [1728,2304)=a1/sq3==a0
    float s = (t >= 1152 && t < 1728) ? A0S3 : A0;
    s *= 0.25f;  // 1/sqrt(16)
    #pragma unroll
    for (int k = 0; k < 16; ++k) Ft1[t * 16 + k] = fc1_w2[k * 2304 + t] * s;
  } else if (t < 2304 + 576) {
    int j = t - 2304;
    // regions: [0,256)=b0 [256,384)=b0/sq3 [384,576)=b1/sq3==b0
    float s = (j >= 256 && j < 384) ? B0S3 : B0;
    s *= 0.25f;
    #pragma unroll
    for (int k = 0; k < 16; ++k) Ft2[j * 16 + k] = fc2_w2[k * 576 + j] * s;
  }
}

// 16-wide dot of one (64B-aligned, contiguous) weight column with h[16]
__device__ __forceinline__ float dotcol(const float* __restrict__ p,
                                        const float* h) {
  const float4* c4 = (const float4*)p;
  float4 c0 = c4[0], c1 = c4[1], c2 = c4[2], c3 = c4[3];
  float a0 = c0.x * h[0], a1 = c0.y * h[1], a2 = c0.z * h[2], a3 = c0.w * h[3];
  a0 = fmaf(c1.x, h[4],  a0); a1 = fmaf(c1.y, h[5],  a1);
  a2 = fmaf(c1.z, h[6],  a2); a3 = fmaf(c1.w, h[7],  a3);
  a0 = fmaf(c2.x, h[8],  a0); a1 = fmaf(c2.y, h[9],  a1);
  a2 = fmaf(c2.z, h[10], a2); a3 = fmaf(c2.w, h[11], a3);
  a0 = fmaf(c3.x, h[12], a0); a1 = fmaf(c3.y, h[13], a1);
  a2 = fmaf(c3.z, h[14], a2); a3 = fmaf(c3.w, h[15], a3);
  return (a0 + a1) + (a2 + a3);
}

// ---------------------------------------------------------------------------
// Edge kernel: one thread per edge. Writes he_new row to out_he and
// atomically accumulates he_new*norm into nf[dst].
// ---------------------------------------------------------------------------
__global__ __launch_bounds__(256) void edge_kernel(
    const float* __restrict__ hn, const float* __restrict__ he,
    const float* __restrict__ edge_vec, const float* __restrict__ emb,
    const float* __restrict__ norm, const float* __restrict__ fc1_w1,
    const float* __restrict__ fc2_w1, const int* __restrict__ edge_index,
    const float* __restrict__ Ft1, const float* __restrict__ Ft2,
    float* __restrict__ out_he, float* __restrict__ nf) {
  __shared__ float tsbuf[256 * 48];
  int e = blockIdx.x * blockDim.x + threadIdx.x;
  if (e >= NE) return;

  float em[10];
  #pragma unroll
  for (int m = 0; m < 10; ++m) em[m] = emb[(size_t)e * 10 + m];

  float h1[16];
  #pragma unroll
  for (int k = 0; k < 16; ++k) {
    float s = 0.f;
    #pragma unroll
    for (int m = 0; m < 10; ++m) s = fmaf(em[m], fc1_w1[m * 16 + k], s);
    h1[k] = s > 0.f ? s * H_SCALE : 0.f;
  }

  float ev0 = edge_vec[e * 3 + 0], ev1 = edge_vec[e * 3 + 1],
        ev2 = edge_vec[e * 3 + 2];
  float rn = rsqrtf(fmaf(ev0, ev0, fmaf(ev1, ev1, ev2 * ev2)));
  float sh0 = SQ3 * ev1 * rn, sh1 = SQ3 * ev2 * rn, sh2 = SQ3 * ev0 * rn;

  int src = edge_index[e], dst = edge_index[NE + e];
  const float* rowe = he + (size_t)e * 40;
  const float* rows = hn + (size_t)src * 40;
  const float* rowd = hn + (size_t)dst * 40;

  float out_s[16], out_g[8], svw[8], vvw[8][3];
  #pragma unroll
  for (int w = 0; w < 16; ++w) out_s[w] = 0.f;
  #pragma unroll
  for (int w = 0; w < 8; ++w) {
    out_g[w] = 0.f; svw[w] = 0.f;
    vvw[w][0] = 0.f; vvw[w][1] = 0.f; vvw[w][2] = 0.f;
  }

  // ---- layer 1, scalar channels (u = 0..47) ----
  #pragma unroll 1
  for (int u = 0; u < 48; ++u) {
    const float* r = (u < 16) ? rowe : ((u < 32) ? rows : rowd);
    int uu = (u < 16) ? u : ((u < 32) ? u - 16 : u - 32);
    float x = r[uu];
    const float* cs_ = Ft1 + (size_t)(u * 16) * 16;          // Wss
    const float* cg_ = Ft1 + (size_t)(768 + u * 8) * 16;     // Wsg
    const float* cv_ = Ft1 + (size_t)(1728 + u * 8) * 16;    // Wsv
    #pragma unroll
    for (int w = 0; w < 16; ++w)
      out_s[w] = fmaf(x, dotcol(cs_ + w * 16, h1), out_s[w]);
    #pragma unroll
    for (int w = 0; w < 8; ++w)
      out_g[w] = fmaf(x, dotcol(cg_ + w * 16, h1), out_g[w]);
    #pragma unroll
    for (int w = 0; w < 8; ++w)
      svw[w] = fmaf(x, dotcol(cv_ + w * 16, h1), svw[w]);
  }

  // ---- layer 1, vector channels (u = 0..23) ----
  #pragma unroll 1
  for (int u = 0; u < 24; ++u) {
    const float* r = (u < 8) ? rowe : ((u < 16) ? rows : rowd);
    int uu = (u < 8) ? u : ((u < 16) ? u - 8 : u - 16);
    float x0 = r[16 + uu * 3 + 0];
    float x1 = r[16 + uu * 3 + 1];
    float x2 = r[16 + uu * 3 + 2];
    float xvs = fmaf(sh0, x0, fmaf(sh1, x1, sh2 * x2));
    const float* cs_ = Ft1 + (size_t)(1152 + u * 16) * 16;   // Wvs
    const float* cg_ = Ft1 + (size_t)(1536 + u * 8) * 16;    // Wvg
    const float* cv_ = Ft1 + (size_t)(2112 + u * 8) * 16;    // Wvv
    #pragma unroll
    for (int w = 0; w < 16; ++w)
      out_s[w] = fmaf(xvs, dotcol(cs_ + w * 16, h1), out_s[w]);
    #pragma unroll
    for (int w = 0; w < 8; ++w)
      out_g[w] = fmaf(xvs, dotcol(cg_ + w * 16, h1), out_g[w]);
    #pragma unroll
    for (int w = 0; w < 8; ++w) {
      float wj = dotcol(cv_ + w * 16, h1);
      vvw[w][0] = fmaf(x0, wj, vvw[w][0]);
      vvw[w][1] = fmaf(x1, wj, vvw[w][1]);
      vvw[w][2] = fmaf(x2, wj, vvw[w][2]);
    }
  }

  // ---- nonlinearity; stash layer-2 inputs in per-thread LDS slot ----
  float* tb = tsbuf + (size_t)threadIdx.x * 48;
  #pragma unroll
  for (int w = 0; w < 16; ++w) tb[w] = C_TANH * tanhf(out_s[w]);
  float tmp_v[8][3];
  #pragma unroll
  for (int w = 0; w < 8; ++w) {
    float g = C_TANH * tanhf(out_g[w]);
    tmp_v[w][0] = g * fmaf(sh0, svw[w], vvw[w][0]);
    tmp_v[w][1] = g * fmaf(sh1, svw[w], vvw[w][1]);
    tmp_v[w][2] = g * fmaf(sh2, svw[w], vvw[w][2]);
    tb[16 + w * 3 + 0] = tmp_v[w][0];
    tb[16 + w * 3 + 1] = tmp_v[w][1];
    tb[16 + w * 3 + 2] = tmp_v[w][2];
    tb[40 + w] = fmaf(sh0, tmp_v[w][0], fmaf(sh1, tmp_v[w][1], sh2 * tmp_v[w][2]));
  }

  float h2[16];
  #pragma unroll
  for (int k = 0; k < 16; ++k) {
    float s = 0.f;
    #pragma unroll
    for (int m = 0; m < 10; ++m) s = fmaf(em[m], fc2_w1[m * 16 + k], s);
    h2[k] = s > 0.f ? s * H_SCALE : 0.f;
  }

  float d_s[16], sv2[8], vv2[8][3];
  #pragma unroll
  for (int w = 0; w < 16; ++w) d_s[w] = 0.f;
  #pragma unroll
  for (int w = 0; w < 8; ++w) {
    sv2[w] = 0.f; vv2[w][0] = 0.f; vv2[w][1] = 0.f; vv2[w][2] = 0.f;
  }

  // ---- layer 2, scalar inputs (u = 0..15) ----
  #pragma unroll 1
  for (int u = 0; u < 16; ++u) {
    float x = tb[u];
    const float* cs_ = Ft2 + (size_t)(u * 16) * 16;          // Wss2
    const float* cv_ = Ft2 + (size_t)(384 + u * 8) * 16;     // Wsv2
    #pragma unroll
    for (int w = 0; w < 16; ++w)
      d_s[w] = fmaf(x, dotcol(cs_ + w * 16, h2), d_s[w]);
    #pragma unroll
    for (int w = 0; w < 8; ++w)
      sv2[w] = fmaf(x, dotcol(cv_ + w * 16, h2), sv2[w]);
  }
  // ---- layer 2, vector inputs (u = 0..7) ----
  #pragma unroll 1
  for (int u = 0; u < 8; ++u) {
    float xt = tb[40 + u];
    float x0 = tb[16 + u * 3 + 0];
    float x1 = tb[16 + u * 3 + 1];
    float x2 = tb[16 + u * 3 + 2];
    const float* cs_ = Ft2 + (size_t)(256 + u * 16) * 16;    // Wvs2
    const float* cv_ = Ft2 + (size_t)(512 + u * 8) * 16;     // Wvv2
    #pragma unroll
    for (int w = 0; w < 16; ++w)
      d_s[w] = fmaf(xt, dotcol(cs_ + w * 16, h2), d_s[w]);
    #pragma unroll
    for (int w = 0; w < 8; ++w) {
      float wj = dotcol(cv_ + w * 16, h2);
      vv2[w][0] = fmaf(x0, wj, vv2[w][0]);
      vv2[w][1] = fmaf(x1, wj, vv2[w][1]);
      vv2[w][2] = fmaf(x2, wj, vv2[w][2]);
    }
  }

  // ---- he_new row + scatter into nf[dst] ----
  float nrm = norm[e];
  float row[40];
  #pragma unroll
  for (int w = 0; w < 16; ++w) row[w] = rowe[w] + d_s[w];
  #pragma unroll
  for (int w = 0; w < 8; ++w) {
    row[16 + w * 3 + 0] = rowe[16 + w * 3 + 0] + fmaf(sh0, sv2[w], vv2[w][0]);
    row[16 + w * 3 + 1] = rowe[16 + w * 3 + 1] + fmaf(sh1, sv2[w], vv2[w][1]);
    row[16 + w * 3 + 2] = rowe[16 + w * 3 + 2] + fmaf(sh2, sv2[w], vv2[w][2]);
  }
  float* o = out_he + (size_t)e * 40;
  #pragma unroll
  for (int j = 0; j < 40; ++j) o[j] = row[j];
  float* nfd = nf + (size_t)dst * 40;
  #pragma unroll
  for (int j = 0; j < 40; ++j) unsafeAtomicAdd(nfd + j, row[j] * nrm);
}

// ---------------------------------------------------------------------------
// Node kernel: one thread per node.
// ---------------------------------------------------------------------------
__global__ __launch_bounds__(256) void node_kernel(
    const float* __restrict__ hn, const float* __restrict__ nf,
    const float* __restrict__ wl1_s, const float* __restrict__ wl1_g,
    const float* __restrict__ wl1_v, const float* __restrict__ wl2_s,
    const float* __restrict__ wl2_v, float* __restrict__ out) {
  int n = blockIdx.x * blockDim.x + threadIdx.x;
  if (n >= NN) return;
  const float* rh = hn + (size_t)n * 40;
  const float* rf = nf + (size_t)n * 40;

  float cs[32], cv[16][3];
  #pragma unroll
  for (int u = 0; u < 16; ++u) cs[u] = rh[u];
  #pragma unroll
  for (int u = 0; u < 16; ++u) cs[16 + u] = rf[u];
  #pragma unroll
  for (int u = 0; u < 8; ++u) {
    cv[u][0] = rh[16 + u * 3 + 0];
    cv[u][1] = rh[16 + u * 3 + 1];
    cv[u][2] = rh[16 + u * 3 + 2];
  }
  #pragma unroll
  for (int u = 0; u < 8; ++u) {
    cv[8 + u][0] = rf[16 + u * 3 + 0];
    cv[8 + u][1] = rf[16 + u * 3 + 1];
    cv[8 + u][2] = rf[16 + u * 3 + 2];
  }

  float l1s[16], l1g[8], l1v[8][3];
  #pragma unroll
  for (int w = 0; w < 16; ++w) l1s[w] = 0.f;
  #pragma unroll
  for (int w = 0; w < 8; ++w) {
    l1g[w] = 0.f; l1v[w][0] = 0.f; l1v[w][1] = 0.f; l1v[w][2] = 0.f;
  }
  #pragma unroll
  for (int u = 0; u < 32; ++u) {
    float x = cs[u];
    #pragma unroll
    for (int w = 0; w < 16; ++w) l1s[w] = fmaf(x, wl1_s[u * 16 + w], l1s[w]);
    #pragma unroll
    for (int w = 0; w < 8; ++w) l1g[w] = fmaf(x, wl1_g[u * 8 + w], l1g[w]);
  }
  #pragma unroll
  for (int u = 0; u < 16; ++u) {
    #pragma unroll
    for (int w = 0; w < 8; ++w) {
      float wv = wl1_v[u * 8 + w];
      l1v[w][0] = fmaf(cv[u][0], wv, l1v[w][0]);
      l1v[w][1] = fmaf(cv[u][1], wv, l1v[w][1]);
      l1v[w][2] = fmaf(cv[u][2], wv, l1v[w][2]);
    }
  }

  float gs[16], gv[8][3];
  #pragma unroll
  for (int w = 0; w < 16; ++w) gs[w] = C_TANH * tanhf(l1s[w] * S32);
  #pragma unroll
  for (int w = 0; w < 8; ++w) {
    float g = C_TANH * tanhf(l1g[w] * S32);
    gv[w][0] = g * l1v[w][0] * S16;
    gv[w][1] = g * l1v[w][1] * S16;
    gv[w][2] = g * l1v[w][2] * S16;
  }

  float l2s[16], l2v[8][3];
  #pragma unroll
  for (int v = 0; v < 16; ++v) l2s[v] = 0.f;
  #pragma unroll
  for (int v = 0; v < 8; ++v) { l2v[v][0] = 0.f; l2v[v][1] = 0.f; l2v[v][2] = 0.f; }
  #pragma unroll
  for (int w = 0; w < 16; ++w) {
    float g = gs[w];
    #pragma unroll
    for (int v = 0; v < 16; ++v) l2s[v] = fmaf(g, wl2_s[w * 16 + v], l2s[v]);
  }
  #pragma unroll
  for (int w = 0; w < 8; ++w) {
    #pragma unroll
    for (int v = 0; v < 8; ++v) {
      float wv = wl2_v[w * 8 + v];
      l2v[v][0] = fmaf(gv[w][0], wv, l2v[v][0]);
      l2v[v][1] = fmaf(gv[w][1], wv, l2v[v][1]);
      l2v[v][2] = fmaf(gv[w][2], wv, l2v[v][2]);
    }
  }

  float* o = out + (size_t)n * 40;
  #pragma unroll
  for (int v = 0; v < 16; ++v) o[v] = rh[v] + l2s[v] * S16;
  #pragma unroll
  for (int v = 0; v < 8; ++v) {
    o[16 + v * 3 + 0] = rh[16 + v * 3 + 0] + l2v[v][0] * S8;
    o[16 + v * 3 + 1] = rh[16 + v * 3 + 1] + l2v[v][1] * S8;
    o[16 + v * 3 + 2] = rh[16 + v * 3 + 2] + l2v[v][2] * S8;
  }
}

extern "C" void kernel_launch(void* const* d_in, const int* in_sizes, int n_in,
                              void* d_out, int out_size, void* d_ws,
                              size_t ws_size, hipStream_t stream) {
  const float* hn       = (const float*)d_in[0];
  const float* he       = (const float*)d_in[1];
  const float* edge_vec = (const float*)d_in[2];
  const float* emb      = (const float*)d_in[3];
  const float* norm     = (const float*)d_in[4];
  const float* fc1_w1   = (const float*)d_in[5];
  const float* fc1_w2   = (const float*)d_in[6];
  const float* fc2_w1   = (const float*)d_in[7];
  const float* fc2_w2   = (const float*)d_in[8];
  const float* wl1_s    = (const float*)d_in[9];
  const float* wl1_g    = (const float*)d_in[10];
  const float* wl1_v    = (const float*)d_in[11];
  const float* wl2_s    = (const float*)d_in[12];
  const float* wl2_v    = (const float*)d_in[13];
  const int*   edge_index = (const int*)d_in[14];

  float* Ft1 = (float*)d_ws;           // 2304*16 floats
  float* Ft2 = Ft1 + 2304 * 16;        // 576*16 floats
  float* nf  = Ft2 + 576 * 16;         // NN*40 floats

  hipMemsetAsync(nf, 0, (size_t)NN * 40 * sizeof(float), stream);
  prep_kernel<<<dim3((2880 + 255) / 256), dim3(256), 0, stream>>>(fc1_w2,
                                                                  fc2_w2, Ft1,
                                                                  Ft2);
  float* out = (float*)d_out;
  edge_kernel<<<dim3((NE + 255) / 256), dim3(256), 0, stream>>>(
      hn, he, edge_vec, emb, norm, fc1_w1, fc2_w1, edge_index, Ft1, Ft2,
      out + (size_t)NN * 40, nf);
  node_kernel<<<dim3((NN + 255) / 256), dim3(256), 0, stream>>>(
      hn, nf, wl1_s, wl1_g, wl1_v, wl2_s, wl2_v, out);
}